// Round 3
// baseline (1758.662 us; speedup 1.0000x reference)
//
#include <hip/hip_runtime.h>
#include <hip/hip_bf16.h>

#define N_NODES 100000
#define N_EDGES 1600000
#define NB 391        // bins of 256 dst-nodes: 100000>>8 = 390.6 -> 391
#define CAP 4608      // per-bin capacity: mean 4092, sigma 64 -> +8 sigma
#define CHUNK 8192    // edges per binfill block

__device__ __forceinline__ float bcast_lane(float v, int k) {
    return __int_as_float(__builtin_amdgcn_readlane(__float_as_int(v), k));
}

// ---------------- binned multisplit fill (+ deg histogram) ----------------
// Groups edges by dst>>8 into per-bin regions, payload packed (src<<8)|(dst&255).
// LDS-staged so global writes are coalesced runs instead of 4B scatter.

__global__ void __launch_bounds__(1024) binfill_kernel(
        const int* __restrict__ src, const int* __restrict__ dst,
        int* __restrict__ deg, int* __restrict__ bincur,
        unsigned* __restrict__ binned, int e) {
    __shared__ int hcount[NB];
    __shared__ int hloc[NB];     // exclusive scan of hcount
    __shared__ int hbase[NB];    // global base for this chunk
    __shared__ unsigned stage[CHUNK];

    int tid = threadIdx.x;
    int base0 = blockIdx.x * CHUNK;

    for (int i = tid; i < NB; i += 1024) hcount[i] = 0;
    __syncthreads();

    int bq[8]; int rq[8]; unsigned pq[8];
    #pragma unroll
    for (int q = 0; q < 8; ++q) {
        int i = base0 + q * 1024 + tid;
        bq[q] = -1;
        if (i < e) {
            int s = src[i], d = dst[i];
            atomicAdd(&deg[d], 1);
            int b = d >> 8;
            bq[q] = b;
            rq[q] = atomicAdd(&hcount[b], 1);
            pq[q] = ((unsigned)s << 8) | (unsigned)(d & 255);
        }
    }
    __syncthreads();

    // reserve global space per bin (independent of the scan below)
    if (tid < NB) hbase[tid] = atomicAdd(&bincur[tid], hcount[tid]);

    // exclusive scan of hcount by wave 0 (7 segments of 64)
    if (tid < 64) {
        int run = 0;
        for (int seg = 0; seg < NB; seg += 64) {
            int idx = seg + tid;
            int d0 = (idx < NB) ? hcount[idx] : 0;
            int v = d0;
            #pragma unroll
            for (int off = 1; off < 64; off <<= 1) {
                int t = __shfl_up(v, off);
                if (tid >= off) v += t;
            }
            if (idx < NB) hloc[idx] = run + v - d0;
            run += __shfl(v, 63);
        }
    }
    __syncthreads();

    // LDS rank-scatter
    #pragma unroll
    for (int q = 0; q < 8; ++q)
        if (bq[q] >= 0) stage[hloc[bq[q]] + rq[q]] = pq[q];
    __syncthreads();

    // coalesced flush: wave w handles bins w, w+16, ...
    int w = tid >> 6, lane = tid & 63;
    for (int b = w; b < NB; b += 16) {
        int len = hcount[b];
        int gb0 = hbase[b];
        int lim = min(len, CAP - gb0);           // overflow guard (never triggers)
        long long gb = (long long)b * CAP + gb0;
        int lo = hloc[b];
        for (int j = lane; j < lim; j += 64) binned[gb + j] = stage[lo + j];
    }
}

// ---------------- binned aggregation (gather + LDS scatter-accumulate) ----
// one block per bin; acc[256][CIN] in LDS; writes mean'd agg coalesced.

template <int CIN>
__global__ void __launch_bounds__(512) binagg_kernel(
        const float* __restrict__ xin, const unsigned* __restrict__ binned,
        const int* __restrict__ bincur, const int* __restrict__ deg,
        float* __restrict__ agg, int n) {
    __shared__ float acc[256 * CIN];
    int tid = threadIdx.x, lane = tid & 63, w = tid >> 6;
    int b = blockIdx.x;

    for (int i = tid; i < 256 * CIN; i += 512) acc[i] = 0.f;
    __syncthreads();

    int count = min(bincur[b], CAP);
    long long boff = (long long)b * CAP;

    if (CIN == 64) {
        for (int base = w * 64; base < count; base += 512) {
            unsigned p = (base + lane < count) ? binned[boff + base + lane] : 0u;
            int m = min(64, count - base);
            #pragma unroll 4
            for (int j = 0; j < m; ++j) {
                unsigned pp = __shfl(p, j);          // uniform j -> readlane
                int s = (int)(pp >> 8), r = (int)(pp & 255u);
                atomicAdd(&acc[r * 64 + lane], xin[(long long)s * 64 + lane]);
            }
        }
    } else {
        // CIN==6: 8 edges per wave step; lane = (edge e8, channel c)
        int e8 = lane >> 3, c = lane & 7;
        for (int base = w * 8; base < count; base += 64) {
            unsigned pl = (lane < 8 && base + lane < count) ? binned[boff + base + lane] : 0u;
            unsigned pp = __shfl(pl, e8);            // bpermute
            int idx = base + e8;
            if (idx < count && c < CIN) {
                int s = (int)(pp >> 8), r = (int)(pp & 255u);
                atomicAdd(&acc[r * CIN + c], xin[(long long)s * CIN + c]);
            }
        }
    }
    __syncthreads();

    // mean + coalesced flush
    for (int i = tid; i < 256 * CIN; i += 512) {
        int r = i / CIN, c = i % CIN;
        int node = b * 256 + r;
        if (node < n) {
            int d = deg[node];
            agg[(long long)node * CIN + c] = acc[i] / (float)max(d, 1);
        }
    }
}

// ---------------- node transform ----------------
// h[lane] = relu( agg_mean[node] . w_l[lane][:] + b[lane] + hin[node] . w_r[lane][:] )
// weights in VGPRs, input broadcast via v_readlane; grid-stride over nodes.

template <int CIN, bool LAST>
__global__ void __launch_bounds__(256) xform_kernel(
        const float* __restrict__ agg, const float* __restrict__ hin,
        const float* __restrict__ w_l, const float* __restrict__ b,
        const float* __restrict__ w_r,
        const float* __restrict__ fc_w, const float* __restrict__ fc_b,
        float* __restrict__ hout, float* __restrict__ out, int n) {
    int lane = threadIdx.x & 63;
    int gwid   = (blockIdx.x * blockDim.x + threadIdx.x) >> 6;
    int nwaves = (gridDim.x * blockDim.x) >> 6;

    float wl[CIN], wr[CIN];
    if (CIN % 4 == 0) {
        const float4* pl = reinterpret_cast<const float4*>(w_l + lane * CIN);
        const float4* pr = reinterpret_cast<const float4*>(w_r + lane * CIN);
        #pragma unroll
        for (int q = 0; q < CIN / 4; ++q) {
            float4 a = pl[q], c = pr[q];
            wl[4*q] = a.x; wl[4*q+1] = a.y; wl[4*q+2] = a.z; wl[4*q+3] = a.w;
            wr[4*q] = c.x; wr[4*q+1] = c.y; wr[4*q+2] = c.z; wr[4*q+3] = c.w;
        }
    } else {
        #pragma unroll
        for (int k = 0; k < CIN; ++k) { wl[k] = w_l[lane*CIN + k]; wr[k] = w_r[lane*CIN + k]; }
    }
    float bias = b[lane];
    float fw0 = 0.f, fw1 = 0.f, fw2 = 0.f;
    if (LAST) { fw0 = fc_w[lane]; fw1 = fc_w[64 + lane]; fw2 = fc_w[128 + lane]; }

    for (int node = gwid; node < n; node += nwaves) {
        float av = (lane < CIN) ? agg[(long long)node * CIN + lane] : 0.f;
        float hv = (lane < CIN) ? hin[(long long)node * CIN + lane] : 0.f;

        float acc = bias;
        #pragma unroll
        for (int k = 0; k < CIN; ++k) {
            float a = bcast_lane(av, k);
            float h = bcast_lane(hv, k);
            acc = fmaf(a, wl[k], fmaf(h, wr[k], acc));
        }
        float hval = fmaxf(acc, 0.f);

        if (!LAST) {
            hout[(long long)node * 64 + lane] = hval;
        } else {
            float p0 = hval * fw0, p1 = hval * fw1, p2 = hval * fw2;
            #pragma unroll
            for (int s = 32; s > 0; s >>= 1) {
                p0 += __shfl_xor(p0, s);
                p1 += __shfl_xor(p1, s);
                p2 += __shfl_xor(p2, s);
            }
            if (lane == 0) {
                out[(long long)node * 3 + 0] = p0 + fc_b[0];
                out[(long long)node * 3 + 1] = p1 + fc_b[1];
                out[(long long)node * 3 + 2] = p2 + fc_b[2];
            }
        }
    }
}

// ---------------- launch ----------------

extern "C" void kernel_launch(void* const* d_in, const int* in_sizes, int n_in,
                              void* d_out, int out_size, void* d_ws, size_t ws_size,
                              hipStream_t stream) {
    const float* x    = (const float*)d_in[0];
    const int*   ei   = (const int*)d_in[1];
    const float* w1_l = (const float*)d_in[2];
    const float* b1   = (const float*)d_in[3];
    const float* w1_r = (const float*)d_in[4];
    const float* w2_l = (const float*)d_in[5];
    const float* b2   = (const float*)d_in[6];
    const float* w2_r = (const float*)d_in[7];
    const float* w3_l = (const float*)d_in[8];
    const float* b3   = (const float*)d_in[9];
    const float* w3_r = (const float*)d_in[10];
    const float* fc_w = (const float*)d_in[11];
    const float* fc_b = (const float*)d_in[12];
    float* out = (float*)d_out;

    const int N = N_NODES;
    const int E = N_EDGES;
    const int* src = ei;
    const int* dst = ei + E;

    size_t off = 0;
    auto alloc = [&](size_t bytes) -> void* {
        void* p = (char*)d_ws + off;
        off += (bytes + 255) & ~size_t(255);
        return p;
    };
    int*      deg    = (int*)alloc(N * sizeof(int));
    int*      bincur = (int*)alloc(NB * sizeof(int));
    unsigned* binned = (unsigned*)alloc((size_t)NB * CAP * sizeof(unsigned));
    float*    agg    = (float*)alloc((size_t)N * 64 * sizeof(float));
    float*    hA     = (float*)alloc((size_t)N * 64 * sizeof(float));
    float*    hB     = (float*)alloc((size_t)N * 64 * sizeof(float));

    // deg and bincur are adjacent in ws -> one memset covers both (incl. pad)
    size_t zlen = ((size_t)(char*)binned) - ((size_t)(char*)deg);
    hipMemsetAsync(deg, 0, zlen, stream);

    int nb_fill = (E + CHUNK - 1) / CHUNK;   // 196
    int nb_x = 1024;                          // xform: grid-stride, 4096 waves

    binfill_kernel<<<nb_fill, 1024, 0, stream>>>(src, dst, deg, bincur, binned, E);

    // layer 1 (6 -> 64)
    binagg_kernel<6><<<NB, 512, 0, stream>>>(x, binned, bincur, deg, agg, N);
    xform_kernel<6, false><<<nb_x, 256, 0, stream>>>(agg, x, w1_l, b1, w1_r,
                                                     nullptr, nullptr, hA, nullptr, N);
    // layer 2 (64 -> 64)
    binagg_kernel<64><<<NB, 512, 0, stream>>>(hA, binned, bincur, deg, agg, N);
    xform_kernel<64, false><<<nb_x, 256, 0, stream>>>(agg, hA, w2_l, b2, w2_r,
                                                      nullptr, nullptr, hB, nullptr, N);
    // layer 3 (64 -> 64) + fused final FC (64 -> 3)
    binagg_kernel<64><<<NB, 512, 0, stream>>>(hB, binned, bincur, deg, agg, N);
    xform_kernel<64, true><<<nb_x, 256, 0, stream>>>(agg, hB, w3_l, b3, w3_r,
                                                     fc_w, fc_b, nullptr, out, N);
}

// Round 4
// 348.819 us; speedup vs baseline: 5.0418x; 5.0418x over previous
//
#include <hip/hip_runtime.h>
#include <hip/hip_bf16.h>

#define N_NODES 100000
#define N_EDGES 1600000
#define NB 391        // bins of 256 dst-nodes
#define CAP 4608      // per-bin capacity: mean 4092, sigma 64 -> +8 sigma
#define CHUNK 8192    // edges per binfill block

__device__ __forceinline__ float bcast_lane(float v, int k) {
    return __int_as_float(__builtin_amdgcn_readlane(__float_as_int(v), k));
}

// ---------------- phase 1: bin edges by dst>>8 ----------------
// payload packed (src<<8)|(dst&255); LDS-staged so global writes are coalesced.

__global__ void __launch_bounds__(1024) binfill_kernel(
        const int* __restrict__ src, const int* __restrict__ dst,
        int* __restrict__ bincur, unsigned* __restrict__ binned, int e) {
    __shared__ int hcount[NB];
    __shared__ int hloc[NB];
    __shared__ int hbase[NB];
    __shared__ unsigned stage[CHUNK];

    int tid = threadIdx.x;
    int base0 = blockIdx.x * CHUNK;

    for (int i = tid; i < NB; i += 1024) hcount[i] = 0;
    __syncthreads();

    int bq[8]; int rq[8]; unsigned pq[8];
    #pragma unroll
    for (int q = 0; q < 8; ++q) {
        int i = base0 + q * 1024 + tid;
        bq[q] = -1;
        if (i < e) {
            int s = src[i], d = dst[i];
            int b = d >> 8;
            bq[q] = b;
            rq[q] = atomicAdd(&hcount[b], 1);
            pq[q] = ((unsigned)s << 8) | (unsigned)(d & 255);
        }
    }
    __syncthreads();

    if (tid < NB) hbase[tid] = atomicAdd(&bincur[tid], hcount[tid]);

    // exclusive scan of hcount by wave 0
    if (tid < 64) {
        int run = 0;
        for (int seg = 0; seg < NB; seg += 64) {
            int idx = seg + tid;
            int d0 = (idx < NB) ? hcount[idx] : 0;
            int v = d0;
            #pragma unroll
            for (int off = 1; off < 64; off <<= 1) {
                int t = __shfl_up(v, off);
                if (tid >= off) v += t;
            }
            if (idx < NB) hloc[idx] = run + v - d0;
            run += __shfl(v, 63);
        }
    }
    __syncthreads();

    #pragma unroll
    for (int q = 0; q < 8; ++q)
        if (bq[q] >= 0) stage[hloc[bq[q]] + rq[q]] = pq[q];
    __syncthreads();

    int w = tid >> 6, lane = tid & 63;
    for (int b = w; b < NB; b += 16) {
        int len = hcount[b];
        int gb0 = hbase[b];
        int lim = min(len, CAP - gb0);
        int lo = hloc[b];
        unsigned* gp = binned + (long long)b * CAP + gb0;
        for (int j = lane; j < lim; j += 64) gp[j] = stage[lo + j];
    }
}

// ---------------- phase 2: scan bin totals ----------------

__global__ void binscan_kernel(const int* __restrict__ bincur,
                               int* __restrict__ binbase, int* __restrict__ row_off) {
    int lane = threadIdx.x;   // 64 threads
    int run = 0;
    for (int seg = 0; seg < NB; seg += 64) {
        int idx = seg + lane;
        int d = (idx < NB) ? bincur[idx] : 0;
        int v = d;
        #pragma unroll
        for (int off = 1; off < 64; off <<= 1) {
            int t = __shfl_up(v, off);
            if (lane >= off) v += t;
        }
        if (idx < NB) binbase[idx] = run + v - d;
        run += __shfl(v, 63);
    }
    if (lane == 0) row_off[N_NODES] = run;
}

// ---------------- phase 3: per-bin CSR finalize ----------------
// counts per node, local scan, LDS rank-scatter, coalesced row_off/src_sorted writes.

__global__ void __launch_bounds__(256) csrfinal_kernel(
        const unsigned* __restrict__ binned, const int* __restrict__ bincur,
        const int* __restrict__ binbase,
        int* __restrict__ row_off, int* __restrict__ src_sorted) {
    __shared__ int cnt[256];
    __shared__ int wsum[4];
    __shared__ unsigned stage[CAP];
    int b = blockIdx.x, tid = threadIdx.x, lane = tid & 63, w = tid >> 6;
    long long boff = (long long)b * CAP;
    int total = min(bincur[b], CAP);
    int base = binbase[b];

    cnt[tid] = 0;
    __syncthreads();
    for (int j = tid; j < total; j += 256) atomicAdd(&cnt[binned[boff + j] & 255u], 1);
    __syncthreads();

    // exclusive scan of cnt[256]
    int d = cnt[tid];
    int v = d;
    #pragma unroll
    for (int off = 1; off < 64; off <<= 1) {
        int t = __shfl_up(v, off);
        if (lane >= off) v += t;
    }
    if (lane == 63) wsum[w] = v;
    __syncthreads();
    int woff = 0;
    for (int ww = 0; ww < w; ++ww) woff += wsum[ww];
    int excl = woff + v - d;

    int node = b * 256 + tid;
    if (node < N_NODES) row_off[node] = base + excl;
    __syncthreads();
    cnt[tid] = excl;          // cursor
    __syncthreads();

    for (int j = tid; j < total; j += 256) {
        unsigned p = binned[boff + j];
        int pos = atomicAdd(&cnt[p & 255u], 1);
        stage[pos] = p >> 8;
    }
    __syncthreads();
    for (int j = tid; j < total; j += 256) src_sorted[base + j] = (int)stage[j];
}

// ---------------- fused layer: mean-aggregate + dual matvec + relu ----------
// one wave per node (grid-stride). Gather: 4 edges x 16 lanes x float4.
// Weights in VGPRs (lane = output channel), inputs broadcast via v_readlane.

template <bool LAST>
__global__ void __launch_bounds__(256) fused64_kernel(
        const float* __restrict__ xin, const int* __restrict__ row_off,
        const int* __restrict__ src_sorted,
        const float* __restrict__ w_l, const float* __restrict__ bvec,
        const float* __restrict__ w_r,
        const float* __restrict__ fc_w, const float* __restrict__ fc_b,
        float* __restrict__ hout, float* __restrict__ out, int n) {
    int lane = threadIdx.x & 63;
    int gwid   = (blockIdx.x * blockDim.x + threadIdx.x) >> 6;
    int nwaves = (gridDim.x * blockDim.x) >> 6;
    int r4 = lane >> 4;            // which of 4 edges in a step
    int c4 = lane & 15;            // which float4 of the 64-ch row

    float wl[64], wr[64];
    {
        const float4* pl = reinterpret_cast<const float4*>(w_l + lane * 64);
        const float4* pr = reinterpret_cast<const float4*>(w_r + lane * 64);
        #pragma unroll
        for (int q = 0; q < 16; ++q) {
            float4 a = pl[q], c = pr[q];
            wl[4*q] = a.x; wl[4*q+1] = a.y; wl[4*q+2] = a.z; wl[4*q+3] = a.w;
            wr[4*q] = c.x; wr[4*q+1] = c.y; wr[4*q+2] = c.z; wr[4*q+3] = c.w;
        }
    }
    float bias = bvec[lane];
    float fw0 = 0.f, fw1 = 0.f, fw2 = 0.f;
    if (LAST) { fw0 = fc_w[lane]; fw1 = fc_w[64 + lane]; fw2 = fc_w[128 + lane]; }

    for (int node = gwid; node < n; node += nwaves) {
        int start = row_off[node], end = row_off[node + 1];
        int deg = end - start;
        float ax = 0.f, ay = 0.f, az = 0.f, aw = 0.f;
        for (int base = start; base < end; base += 64) {
            int cnt = min(64, end - base);
            int sid = (lane < cnt) ? src_sorted[base + lane] : 0;
            for (int jj = 0; jj < cnt; jj += 4) {
                int eidx = jj + r4;
                int s = __shfl(sid, eidx);
                const float4 v = *reinterpret_cast<const float4*>(xin + s * 64 + (c4 << 2));
                if (eidx < cnt) { ax += v.x; ay += v.y; az += v.z; aw += v.w; }
            }
        }
        #pragma unroll
        for (int sh = 16; sh <= 32; sh <<= 1) {
            ax += __shfl_xor(ax, sh); ay += __shfl_xor(ay, sh);
            az += __shfl_xor(az, sh); aw += __shfl_xor(aw, sh);
        }
        float rs = 1.0f / (float)max(deg, 1);
        float arrA[4] = {ax * rs, ay * rs, az * rs, aw * rs};
        float4 h4 = *reinterpret_cast<const float4*>(xin + node * 64 + (c4 << 2));
        float arrH[4] = {h4.x, h4.y, h4.z, h4.w};

        float acc = bias;
        #pragma unroll
        for (int k = 0; k < 64; ++k) {
            float a = bcast_lane(arrA[k & 3], k >> 2);
            float h = bcast_lane(arrH[k & 3], k >> 2);
            acc = fmaf(a, wl[k], fmaf(h, wr[k], acc));
        }
        float hval = fmaxf(acc, 0.f);

        if (!LAST) {
            hout[node * 64 + lane] = hval;
        } else {
            float p0 = hval * fw0, p1 = hval * fw1, p2 = hval * fw2;
            #pragma unroll
            for (int s = 32; s > 0; s >>= 1) {
                p0 += __shfl_xor(p0, s);
                p1 += __shfl_xor(p1, s);
                p2 += __shfl_xor(p2, s);
            }
            if (lane == 0) {
                out[node * 3 + 0] = p0 + fc_b[0];
                out[node * 3 + 1] = p1 + fc_b[1];
                out[node * 3 + 2] = p2 + fc_b[2];
            }
        }
    }
}

// layer 1: CIN=6. Gather: 8 edges x 8 lanes (6 channels used).
__global__ void __launch_bounds__(256) fused6_kernel(
        const float* __restrict__ xin, const int* __restrict__ row_off,
        const int* __restrict__ src_sorted,
        const float* __restrict__ w_l, const float* __restrict__ bvec,
        const float* __restrict__ w_r,
        float* __restrict__ hout, int n) {
    int lane = threadIdx.x & 63;
    int gwid   = (blockIdx.x * blockDim.x + threadIdx.x) >> 6;
    int nwaves = (gridDim.x * blockDim.x) >> 6;
    int e8 = lane >> 3, c = lane & 7;

    float wl[6], wr[6];
    #pragma unroll
    for (int k = 0; k < 6; ++k) { wl[k] = w_l[lane*6 + k]; wr[k] = w_r[lane*6 + k]; }
    float bias = bvec[lane];

    for (int node = gwid; node < n; node += nwaves) {
        int start = row_off[node], end = row_off[node + 1];
        int deg = end - start;
        float acc = 0.f;
        for (int base = start; base < end; base += 64) {
            int cnt = min(64, end - base);
            int sid = (lane < cnt) ? src_sorted[base + lane] : 0;
            for (int jj = 0; jj < cnt; jj += 8) {
                int eidx = jj + e8;
                int s = __shfl(sid, eidx);
                bool valid = (eidx < cnt) && (c < 6);
                float v = valid ? xin[s * 6 + c] : 0.f;
                acc += v;
            }
        }
        #pragma unroll
        for (int sh = 8; sh <= 32; sh <<= 1) acc += __shfl_xor(acc, sh);
        float rs = 1.0f / (float)max(deg, 1);
        float av = acc * rs;                                   // channel c, replicated
        float hv = (lane < 6) ? xin[node * 6 + lane] : 0.f;

        float o = bias;
        #pragma unroll
        for (int k = 0; k < 6; ++k) {
            o = fmaf(bcast_lane(av, k), wl[k], fmaf(bcast_lane(hv, k), wr[k], o));
        }
        hout[node * 64 + lane] = fmaxf(o, 0.f);
    }
}

// ---------------- launch ----------------

extern "C" void kernel_launch(void* const* d_in, const int* in_sizes, int n_in,
                              void* d_out, int out_size, void* d_ws, size_t ws_size,
                              hipStream_t stream) {
    const float* x    = (const float*)d_in[0];
    const int*   ei   = (const int*)d_in[1];
    const float* w1_l = (const float*)d_in[2];
    const float* b1   = (const float*)d_in[3];
    const float* w1_r = (const float*)d_in[4];
    const float* w2_l = (const float*)d_in[5];
    const float* b2   = (const float*)d_in[6];
    const float* w2_r = (const float*)d_in[7];
    const float* w3_l = (const float*)d_in[8];
    const float* b3   = (const float*)d_in[9];
    const float* w3_r = (const float*)d_in[10];
    const float* fc_w = (const float*)d_in[11];
    const float* fc_b = (const float*)d_in[12];
    float* out = (float*)d_out;

    const int N = N_NODES;
    const int E = N_EDGES;
    const int* src = ei;
    const int* dst = ei + E;

    size_t off = 0;
    auto alloc = [&](size_t bytes) -> void* {
        void* p = (char*)d_ws + off;
        off += (bytes + 255) & ~size_t(255);
        return p;
    };
    int*      bincur     = (int*)alloc(NB * sizeof(int));
    int*      binbase    = (int*)alloc(NB * sizeof(int));
    unsigned* binned     = (unsigned*)alloc((size_t)NB * CAP * sizeof(unsigned));
    int*      row_off    = (int*)alloc((N + 1) * sizeof(int));
    int*      src_sorted = (int*)alloc((size_t)E * sizeof(int));
    float*    hA         = (float*)alloc((size_t)N * 64 * sizeof(float));
    float*    hB         = (float*)alloc((size_t)N * 64 * sizeof(float));

    hipMemsetAsync(bincur, 0, NB * sizeof(int), stream);

    int nb_fill = (E + CHUNK - 1) / CHUNK;

    binfill_kernel<<<nb_fill, 1024, 0, stream>>>(src, dst, bincur, binned, E);
    binscan_kernel<<<1, 64, 0, stream>>>(bincur, binbase, row_off);
    csrfinal_kernel<<<NB, 256, 0, stream>>>(binned, bincur, binbase, row_off, src_sorted);

    // layer 1 (6 -> 64)
    fused6_kernel<<<1024, 256, 0, stream>>>(x, row_off, src_sorted, w1_l, b1, w1_r, hA, N);
    // layer 2 (64 -> 64)
    fused64_kernel<false><<<768, 256, 0, stream>>>(hA, row_off, src_sorted, w2_l, b2, w2_r,
                                                   nullptr, nullptr, hB, nullptr, N);
    // layer 3 (64 -> 64) + fused final FC (64 -> 3)
    fused64_kernel<true><<<768, 256, 0, stream>>>(hB, row_off, src_sorted, w3_l, b3, w3_r,
                                                  fc_w, fc_b, nullptr, out, N);
}

// Round 5
// 346.972 us; speedup vs baseline: 5.0686x; 1.0053x over previous
//
#include <hip/hip_runtime.h>
#include <hip/hip_bf16.h>

#define N_NODES 100000
#define N_EDGES 1600000
#define NB 391        // bins of 256 dst-nodes
#define CAP 4608      // per-bin capacity: mean 4092, sigma 64 -> +8 sigma
#define CHUNK 8192    // edges per binfill block

__device__ __forceinline__ float bcast_lane(float v, int k) {
    return __int_as_float(__builtin_amdgcn_readlane(__float_as_int(v), k));
}

// ---------------- phase 1: bin edges by dst>>8 ----------------
// payload packed (src<<8)|(dst&255); LDS-staged so global writes are coalesced.

__global__ void __launch_bounds__(1024) binfill_kernel(
        const int* __restrict__ src, const int* __restrict__ dst,
        int* __restrict__ bincur, unsigned* __restrict__ binned, int e) {
    __shared__ int hcount[NB];
    __shared__ int hloc[NB];
    __shared__ int hbase[NB];
    __shared__ unsigned stage[CHUNK];

    int tid = threadIdx.x;
    int base0 = blockIdx.x * CHUNK;

    for (int i = tid; i < NB; i += 1024) hcount[i] = 0;
    __syncthreads();

    int bq[8]; int rq[8]; unsigned pq[8];
    #pragma unroll
    for (int q = 0; q < 8; ++q) {
        int i = base0 + q * 1024 + tid;
        bq[q] = -1;
        if (i < e) {
            int s = src[i], d = dst[i];
            int b = d >> 8;
            bq[q] = b;
            rq[q] = atomicAdd(&hcount[b], 1);
            pq[q] = ((unsigned)s << 8) | (unsigned)(d & 255);
        }
    }
    __syncthreads();

    if (tid < NB) hbase[tid] = atomicAdd(&bincur[tid], hcount[tid]);

    // exclusive scan of hcount by wave 0
    if (tid < 64) {
        int run = 0;
        for (int seg = 0; seg < NB; seg += 64) {
            int idx = seg + tid;
            int d0 = (idx < NB) ? hcount[idx] : 0;
            int v = d0;
            #pragma unroll
            for (int off = 1; off < 64; off <<= 1) {
                int t = __shfl_up(v, off);
                if (tid >= off) v += t;
            }
            if (idx < NB) hloc[idx] = run + v - d0;
            run += __shfl(v, 63);
        }
    }
    __syncthreads();

    #pragma unroll
    for (int q = 0; q < 8; ++q)
        if (bq[q] >= 0) stage[hloc[bq[q]] + rq[q]] = pq[q];
    __syncthreads();

    int w = tid >> 6, lane = tid & 63;
    for (int b = w; b < NB; b += 16) {
        int len = hcount[b];
        int gb0 = hbase[b];
        int lim = min(len, CAP - gb0);
        int lo = hloc[b];
        unsigned* gp = binned + (long long)b * CAP + gb0;
        for (int j = lane; j < lim; j += 64) gp[j] = stage[lo + j];
    }
}

// ---------------- phase 2: scan bin totals ----------------

__global__ void binscan_kernel(const int* __restrict__ bincur,
                               int* __restrict__ binbase, int* __restrict__ row_off) {
    int lane = threadIdx.x;   // 64 threads
    int run = 0;
    for (int seg = 0; seg < NB; seg += 64) {
        int idx = seg + lane;
        int d = (idx < NB) ? bincur[idx] : 0;
        int v = d;
        #pragma unroll
        for (int off = 1; off < 64; off <<= 1) {
            int t = __shfl_up(v, off);
            if (lane >= off) v += t;
        }
        if (idx < NB) binbase[idx] = run + v - d;
        run += __shfl(v, 63);
    }
    if (lane == 0) row_off[N_NODES] = run;
}

// ---------------- phase 3: per-bin CSR finalize ----------------

__global__ void __launch_bounds__(256) csrfinal_kernel(
        const unsigned* __restrict__ binned, const int* __restrict__ bincur,
        const int* __restrict__ binbase,
        int* __restrict__ row_off, int* __restrict__ src_sorted) {
    __shared__ int cnt[256];
    __shared__ int wsum[4];
    __shared__ unsigned stage[CAP];
    int b = blockIdx.x, tid = threadIdx.x, lane = tid & 63, w = tid >> 6;
    long long boff = (long long)b * CAP;
    int total = min(bincur[b], CAP);
    int base = binbase[b];

    cnt[tid] = 0;
    __syncthreads();
    for (int j = tid; j < total; j += 256) atomicAdd(&cnt[binned[boff + j] & 255u], 1);
    __syncthreads();

    int d = cnt[tid];
    int v = d;
    #pragma unroll
    for (int off = 1; off < 64; off <<= 1) {
        int t = __shfl_up(v, off);
        if (lane >= off) v += t;
    }
    if (lane == 63) wsum[w] = v;
    __syncthreads();
    int woff = 0;
    for (int ww = 0; ww < w; ++ww) woff += wsum[ww];
    int excl = woff + v - d;

    int node = b * 256 + tid;
    if (node < N_NODES) row_off[node] = base + excl;
    __syncthreads();
    cnt[tid] = excl;          // cursor
    __syncthreads();

    for (int j = tid; j < total; j += 256) {
        unsigned p = binned[boff + j];
        int pos = atomicAdd(&cnt[p & 255u], 1);
        stage[pos] = p >> 8;
    }
    __syncthreads();
    for (int j = tid; j < total; j += 256) src_sorted[base + j] = (int)stage[j];
}

// ---------------- fused layer: mean-aggregate + dual matvec + relu ----------
// one wave per node (grid-stride). Gather: 4 edges x 16 lanes x float4.
// Weights in VGPRs (lane = output channel), inputs broadcast via v_readlane.
// __launch_bounds__(256,3): 170-VGPR budget so the 128 weight regs stay
// register-resident (R4's default budget forced per-node weight reloads).

template <bool LAST>
__global__ void __launch_bounds__(256, 3) fused64_kernel(
        const float* __restrict__ xin, const int* __restrict__ row_off,
        const int* __restrict__ src_sorted,
        const float* __restrict__ w_l, const float* __restrict__ bvec,
        const float* __restrict__ w_r,
        const float* __restrict__ fc_w, const float* __restrict__ fc_b,
        float* __restrict__ hout, float* __restrict__ out, int n) {
    int lane = threadIdx.x & 63;
    int gwid   = (blockIdx.x * blockDim.x + threadIdx.x) >> 6;
    int nwaves = (gridDim.x * blockDim.x) >> 6;
    int r4 = lane >> 4;            // which of 4 edges in a step
    int c4 = lane & 15;            // which float4 of the 64-ch row

    float wl[64], wr[64];
    {
        const float4* pl = reinterpret_cast<const float4*>(w_l + lane * 64);
        const float4* pr = reinterpret_cast<const float4*>(w_r + lane * 64);
        #pragma unroll
        for (int q = 0; q < 16; ++q) {
            float4 a = pl[q], c = pr[q];
            wl[4*q] = a.x; wl[4*q+1] = a.y; wl[4*q+2] = a.z; wl[4*q+3] = a.w;
            wr[4*q] = c.x; wr[4*q+1] = c.y; wr[4*q+2] = c.z; wr[4*q+3] = c.w;
        }
    }
    float bias = bvec[lane];
    float fw0 = 0.f, fw1 = 0.f, fw2 = 0.f;
    if (LAST) { fw0 = fc_w[lane]; fw1 = fc_w[64 + lane]; fw2 = fc_w[128 + lane]; }

    for (int node = gwid; node < n; node += nwaves) {
        int start = row_off[node], end = row_off[node + 1];
        int deg = end - start;
        // issue self-row load early; overlaps the gather
        float4 h4 = *reinterpret_cast<const float4*>(xin + node * 64 + (c4 << 2));
        float ax = 0.f, ay = 0.f, az = 0.f, aw = 0.f;
        for (int base = start; base < end; base += 64) {
            int cnt = min(64, end - base);
            int sid = (lane < cnt) ? src_sorted[base + lane] : 0;
            for (int jj = 0; jj < cnt; jj += 4) {
                int eidx = jj + r4;
                int s = __shfl(sid, eidx);
                const float4 v = *reinterpret_cast<const float4*>(xin + s * 64 + (c4 << 2));
                if (eidx < cnt) { ax += v.x; ay += v.y; az += v.z; aw += v.w; }
            }
        }
        #pragma unroll
        for (int sh = 16; sh <= 32; sh <<= 1) {
            ax += __shfl_xor(ax, sh); ay += __shfl_xor(ay, sh);
            az += __shfl_xor(az, sh); aw += __shfl_xor(aw, sh);
        }
        float rs = 1.0f / (float)max(deg, 1);
        float arrA[4] = {ax * rs, ay * rs, az * rs, aw * rs};
        float arrH[4] = {h4.x, h4.y, h4.z, h4.w};

        float acc = bias;
        #pragma unroll
        for (int k = 0; k < 64; ++k) {
            float a = bcast_lane(arrA[k & 3], k >> 2);
            float h = bcast_lane(arrH[k & 3], k >> 2);
            acc = fmaf(a, wl[k], fmaf(h, wr[k], acc));
        }
        float hval = fmaxf(acc, 0.f);

        if (!LAST) {
            hout[node * 64 + lane] = hval;
        } else {
            float p0 = hval * fw0, p1 = hval * fw1, p2 = hval * fw2;
            #pragma unroll
            for (int s = 32; s > 0; s >>= 1) {
                p0 += __shfl_xor(p0, s);
                p1 += __shfl_xor(p1, s);
                p2 += __shfl_xor(p2, s);
            }
            if (lane == 0) {
                out[node * 3 + 0] = p0 + fc_b[0];
                out[node * 3 + 1] = p1 + fc_b[1];
                out[node * 3 + 2] = p2 + fc_b[2];
            }
        }
    }
}

// layer 1: CIN=6. Gather: 8 edges x 8 lanes (6 channels used).
__global__ void __launch_bounds__(256) fused6_kernel(
        const float* __restrict__ xin, const int* __restrict__ row_off,
        const int* __restrict__ src_sorted,
        const float* __restrict__ w_l, const float* __restrict__ bvec,
        const float* __restrict__ w_r,
        float* __restrict__ hout, int n) {
    int lane = threadIdx.x & 63;
    int gwid   = (blockIdx.x * blockDim.x + threadIdx.x) >> 6;
    int nwaves = (gridDim.x * blockDim.x) >> 6;
    int e8 = lane >> 3, c = lane & 7;

    float wl[6], wr[6];
    #pragma unroll
    for (int k = 0; k < 6; ++k) { wl[k] = w_l[lane*6 + k]; wr[k] = w_r[lane*6 + k]; }
    float bias = bvec[lane];

    for (int node = gwid; node < n; node += nwaves) {
        int start = row_off[node], end = row_off[node + 1];
        int deg = end - start;
        float acc = 0.f;
        for (int base = start; base < end; base += 64) {
            int cnt = min(64, end - base);
            int sid = (lane < cnt) ? src_sorted[base + lane] : 0;
            for (int jj = 0; jj < cnt; jj += 8) {
                int eidx = jj + e8;
                int s = __shfl(sid, eidx);
                bool valid = (eidx < cnt) && (c < 6);
                float v = valid ? xin[s * 6 + c] : 0.f;
                acc += v;
            }
        }
        #pragma unroll
        for (int sh = 8; sh <= 32; sh <<= 1) acc += __shfl_xor(acc, sh);
        float rs = 1.0f / (float)max(deg, 1);
        float av = acc * rs;
        float hv = (lane < 6) ? xin[node * 6 + lane] : 0.f;

        float o = bias;
        #pragma unroll
        for (int k = 0; k < 6; ++k) {
            o = fmaf(bcast_lane(av, k), wl[k], fmaf(bcast_lane(hv, k), wr[k], o));
        }
        hout[node * 64 + lane] = fmaxf(o, 0.f);
    }
}

// ---------------- launch ----------------

extern "C" void kernel_launch(void* const* d_in, const int* in_sizes, int n_in,
                              void* d_out, int out_size, void* d_ws, size_t ws_size,
                              hipStream_t stream) {
    const float* x    = (const float*)d_in[0];
    const int*   ei   = (const int*)d_in[1];
    const float* w1_l = (const float*)d_in[2];
    const float* b1   = (const float*)d_in[3];
    const float* w1_r = (const float*)d_in[4];
    const float* w2_l = (const float*)d_in[5];
    const float* b2   = (const float*)d_in[6];
    const float* w2_r = (const float*)d_in[7];
    const float* w3_l = (const float*)d_in[8];
    const float* b3   = (const float*)d_in[9];
    const float* w3_r = (const float*)d_in[10];
    const float* fc_w = (const float*)d_in[11];
    const float* fc_b = (const float*)d_in[12];
    float* out = (float*)d_out;

    const int N = N_NODES;
    const int E = N_EDGES;
    const int* src = ei;
    const int* dst = ei + E;

    size_t off = 0;
    auto alloc = [&](size_t bytes) -> void* {
        void* p = (char*)d_ws + off;
        off += (bytes + 255) & ~size_t(255);
        return p;
    };
    int*      bincur     = (int*)alloc(NB * sizeof(int));
    int*      binbase    = (int*)alloc(NB * sizeof(int));
    unsigned* binned     = (unsigned*)alloc((size_t)NB * CAP * sizeof(unsigned));
    int*      row_off    = (int*)alloc((N + 1) * sizeof(int));
    int*      src_sorted = (int*)alloc((size_t)E * sizeof(int));
    float*    hA         = (float*)alloc((size_t)N * 64 * sizeof(float));
    float*    hB         = (float*)alloc((size_t)N * 64 * sizeof(float));

    hipMemsetAsync(bincur, 0, NB * sizeof(int), stream);

    int nb_fill = (E + CHUNK - 1) / CHUNK;

    binfill_kernel<<<nb_fill, 1024, 0, stream>>>(src, dst, bincur, binned, E);
    binscan_kernel<<<1, 64, 0, stream>>>(bincur, binbase, row_off);
    csrfinal_kernel<<<NB, 256, 0, stream>>>(binned, bincur, binbase, row_off, src_sorted);

    // layer 1 (6 -> 64)
    fused6_kernel<<<1024, 256, 0, stream>>>(x, row_off, src_sorted, w1_l, b1, w1_r, hA, N);
    // layer 2 (64 -> 64)
    fused64_kernel<false><<<768, 256, 0, stream>>>(hA, row_off, src_sorted, w2_l, b2, w2_r,
                                                   nullptr, nullptr, hB, nullptr, N);
    // layer 3 (64 -> 64) + fused final FC (64 -> 3)
    fused64_kernel<true><<<768, 256, 0, stream>>>(hB, row_off, src_sorted, w3_l, b3, w3_r,
                                                  fc_w, fc_b, nullptr, out, N);
}